// Round 5
// baseline (122.411 us; speedup 1.0000x reference)
//
#include <hip/hip_runtime.h>
#include <stdint.h>

// MajFC: out[b,c] = 2.25 * sum_g clip(sum_{k<3} sign(x[b,3g+k])*sign(w[c,3g+k]), -1, 1)
// Sign-only bitplanes (absmax 0.0 verified R3/R4): t = px ^ pw,
// clip(group) = 1 - 2*maj(t0,t1,t2), out = 2.25*(1024 - 2*popc_total).
//
// Permutation trick (R4): popc-sum is invariant under any (group,slot)->(bit,plane)
// bijection applied identically to x and w. element e = 768q + 12l + 3j + k ->
// plane [q][3j+k] bit l. Each lane packs 3 contiguous float4s (perfectly coalesced).
//
// Single dispatch (R5): 512 blocks pack disjoint slices, release per-block MAGIC
// flags; block 511's wave 0 sweeps all 512 flags (8/lane, s_sleep between polls)
// and release-stores one GO flag; every block's thread 0 poll-acquires GO, then
// __syncthreads. ~576 spinning threads total vs R3's 131k (the R3 regression was
// spin-traffic saturating the coherence fabric). MAGIC flags need no init on the
// 0xAA-poisoned ws. 0 LDS + ~48 VGPR -> all 512 blocks co-resident (no deadlock).

#define B_SZ  256
#define C_IN  3072
#define C_OUT 1024
#define CHUNKS_W 4096          // 1024 w-rows * 4 chunks
#define CHUNKS_TOT 5120        // + 256 x-rows * 4 chunks
#define NBLK  512
#define MAGIC 0x51C0FFEE00C0DE42ull

// ws layout:
//   wpk  : [q][c][12] uint64 -> 393216 B  (96 B contiguous per (q,c))
//   xpk  : [b][q][12] uint64 ->  98304 B  (wave-uniform scalar reads in phase 3)
//   flags: [512] + go at [768], after 4 KB gap

__global__ __launch_bounds__(256, 2) void maj_fused(
    const float* __restrict__ x, const float* __restrict__ w,
    uint64_t* __restrict__ wpk, uint64_t* __restrict__ xpk,
    uint64_t* __restrict__ flags, float* __restrict__ out)
{
    const int tid = threadIdx.x;
    const int lane = tid & 63;
    const int blk = blockIdx.x;
    const int wvg = blk * 4 + (tid >> 6);       // global wave id, 0..2047

    // ---- Phase 1: pack (grid-strided over 5120 chunk-jobs; j is wave-uniform)
    for (int j = wvg; j < CHUNKS_TOT; j += 2048) {
        const float* src;
        uint64_t* dst;
        if (j < CHUNKS_W) {
            int c = j >> 2, q = j & 3;
            src = w + (size_t)c * C_IN + q * 768;
            dst = wpk + ((size_t)q * C_OUT + c) * 12;
        } else {
            int id = j - CHUNKS_W;
            int b = id >> 2, q = id & 3;
            src = x + (size_t)b * C_IN + q * 768;
            dst = xpk + ((size_t)b * 4 + q) * 12;
        }
        const float4* s4 = (const float4*)(src + 12 * lane);
        float4 f0 = s4[0], f1 = s4[1], f2 = s4[2];
        float v[12] = {f0.x, f0.y, f0.z, f0.w,
                       f1.x, f1.y, f1.z, f1.w,
                       f2.x, f2.y, f2.z, f2.w};
        uint64_t pl[12];
#pragma unroll
        for (int m = 0; m < 12; ++m)
            pl[m] = __ballot(v[m] > 0.0f);
        if (lane == 0) {
#pragma unroll
            for (int m = 0; m < 12; ++m)
                dst[m] = pl[m];
        }
    }
    __syncthreads();   // all block stores drained (compiler emits vmcnt(0))
    if (tid == 0)
        __hip_atomic_store(&flags[blk], MAGIC, __ATOMIC_RELEASE, __HIP_MEMORY_SCOPE_AGENT);

    // ---- Phase 2: tree sync. Block 511 wave 0 sweeps; everyone polls GO.
    if (blk == NBLK - 1 && tid < 64) {
#pragma unroll
        for (int i = 0; i < 8; ++i) {
            const uint64_t* f = &flags[lane * 8 + i];
            while (__hip_atomic_load(f, __ATOMIC_ACQUIRE,
                                     __HIP_MEMORY_SCOPE_AGENT) != MAGIC)
                __builtin_amdgcn_s_sleep(1);
        }
        if (tid == 0)
            __hip_atomic_store(&flags[768], MAGIC, __ATOMIC_RELEASE,
                               __HIP_MEMORY_SCOPE_AGENT);
    }
    if (tid == 0) {
        while (__hip_atomic_load(&flags[768], __ATOMIC_ACQUIRE,
                                 __HIP_MEMORY_SCOPE_AGENT) != MAGIC)
            __builtin_amdgcn_s_sleep(2);
    }
    __syncthreads();

    // ---- Phase 3: majority reduction (identical to R4 maj_main; grid matches).
    int b0 = (blk >> 2) * 2;
    int c  = (blk & 3) * 256 + tid;

    int acc0 = 0, acc1 = 0;
#pragma unroll
    for (int q = 0; q < 4; ++q) {
        const uint64_t* wb = wpk + ((size_t)q * C_OUT + c) * 12;    // 96 B contiguous
        const uint64_t* x0 = xpk + ((size_t)(b0 + 0) * 4 + q) * 12; // wave-uniform
        const uint64_t* x1 = xpk + ((size_t)(b0 + 1) * 4 + q) * 12;
        uint64_t Wv[12];
#pragma unroll
        for (int m = 0; m < 12; ++m) Wv[m] = wb[m];
#pragma unroll
        for (int j = 0; j < 4; ++j) {
            uint64_t t0 = x0[3 * j + 0] ^ Wv[3 * j + 0];
            uint64_t t1 = x0[3 * j + 1] ^ Wv[3 * j + 1];
            uint64_t t2 = x0[3 * j + 2] ^ Wv[3 * j + 2];
            acc0 += __popcll((t0 & t1) | (t2 & (t0 | t1)));
            uint64_t u0 = x1[3 * j + 0] ^ Wv[3 * j + 0];
            uint64_t u1 = x1[3 * j + 1] ^ Wv[3 * j + 1];
            uint64_t u2 = x1[3 * j + 2] ^ Wv[3 * j + 2];
            acc1 += __popcll((u0 & u1) | (u2 & (u0 | u1)));
        }
    }
    out[(size_t)(b0 + 0) * C_OUT + c] = 2304.0f - 4.5f * (float)acc0;
    out[(size_t)(b0 + 1) * C_OUT + c] = 2304.0f - 4.5f * (float)acc1;
}

extern "C" void kernel_launch(void* const* d_in, const int* in_sizes, int n_in,
                              void* d_out, int out_size, void* d_ws, size_t ws_size,
                              hipStream_t stream) {
    const float* x = (const float*)d_in[0];   // [256, 3072] f32
    const float* w = (const float*)d_in[1];   // [1024, 3072] f32
    float* out = (float*)d_out;               // [256, 1024] f32

    uint64_t* wpk   = (uint64_t*)d_ws;
    uint64_t* xpk   = (uint64_t*)((char*)d_ws + 393216);
    uint64_t* flags = (uint64_t*)((char*)d_ws + 393216 + 98304 + 4096);

    maj_fused<<<NBLK, 256, 0, stream>>>(x, w, wpk, xpk, flags, out);
}

// Round 6
// 71.638 us; speedup vs baseline: 1.7087x; 1.7087x over previous
//
#include <hip/hip_runtime.h>
#include <stdint.h>

// MajFC: out[b,c] = 2.25 * sum_g clip(sum_{k<3} sign(x[b,3g+k])*sign(w[c,3g+k]), -1, 1)
// Sign-only bitplanes (absmax 0.0 verified R3-R5): t = px ^ pw,
// clip(group) = 1 - 2*maj(t0,t1,t2), out = 2.25*(1024 - 2*popc_total).
//
// Permutation trick: popc-sum is invariant under any (group,slot)->(bit,plane)
// bijection applied identically to x and w: element e = 768q + 12l + 3j + k ->
// plane [q][3j+k] bit l. Each lane packs 3 contiguous float4s (coalesced).
//
// Structure (R6): two dispatches, NO cross-block flag sync — R3/R5 measured that
// per-block agent release/acquire fences cost ~60us here (buffer_wbl2/inv scans
// against the harness's freshly-dirtied L2), insensitive to spinner count.
//   1) pack_w: w -> wpk[q][c][12] (1024 blocks, 1 chunk-job per wave)
//   2) maj_main: packs its own 2 x-rows in-block via ballots->LDS (768 B),
//      then the majority reduction. No xpk global round-trip.

#define C_IN  3072
#define C_OUT 1024

__global__ __launch_bounds__(256) void pack_w(const float* __restrict__ w,
                                              uint64_t* __restrict__ wpk) {
    int j    = blockIdx.x * 4 + (threadIdx.x >> 6);   // chunk-job 0..4095
    int lane = threadIdx.x & 63;
    int c = j >> 2, q = j & 3;
    const float* src = w + (size_t)c * C_IN + q * 768;
    const float4* s4 = (const float4*)(src + 12 * lane);
    float4 f0 = s4[0], f1 = s4[1], f2 = s4[2];
    float v[12] = {f0.x, f0.y, f0.z, f0.w,
                   f1.x, f1.y, f1.z, f1.w,
                   f2.x, f2.y, f2.z, f2.w};
    uint64_t pl[12];
#pragma unroll
    for (int m = 0; m < 12; ++m)
        pl[m] = __ballot(v[m] > 0.0f);
    if (lane == 0) {
        uint64_t* dst = wpk + ((size_t)q * C_OUT + c) * 12;   // 96 B contiguous
#pragma unroll
        for (int m = 0; m < 12; ++m)
            dst[m] = pl[m];
    }
}

__global__ __launch_bounds__(256) void maj_main(const float* __restrict__ x,
                                                const uint64_t* __restrict__ wpk,
                                                float* __restrict__ out) {
    __shared__ uint64_t xs[96];          // [bi(2)][q(4)][12]
    int tid  = threadIdx.x;
    int lane = tid & 63;
    int wv   = tid >> 6;                 // 0..3
    int blk  = blockIdx.x;               // 0..511
    int b0   = (blk >> 2) * 2;
    int c    = (blk & 3) * 256 + tid;

    // ---- in-block x-pack: 8 chunk-jobs (bi,q), 2 per wave ----
#pragma unroll
    for (int i = 0; i < 2; ++i) {
        int job = wv * 2 + i;            // 0..7
        int bi = job >> 2, q = job & 3;
        const float* src = x + (size_t)(b0 + bi) * C_IN + q * 768;
        const float4* s4 = (const float4*)(src + 12 * lane);
        float4 f0 = s4[0], f1 = s4[1], f2 = s4[2];
        float v[12] = {f0.x, f0.y, f0.z, f0.w,
                       f1.x, f1.y, f1.z, f1.w,
                       f2.x, f2.y, f2.z, f2.w};
#pragma unroll
        for (int m = 0; m < 12; ++m) {
            uint64_t pl = __ballot(v[m] > 0.0f);
            if (lane == 0) xs[job * 12 + m] = pl;
        }
    }
    __syncthreads();

    // ---- majority reduction ----
    int acc0 = 0, acc1 = 0;
#pragma unroll
    for (int q = 0; q < 4; ++q) {
        const uint64_t* wb = wpk + ((size_t)q * C_OUT + c) * 12;  // 96 B contiguous
        uint64_t Wv[12];
#pragma unroll
        for (int m = 0; m < 12; ++m) Wv[m] = wb[m];
        const uint64_t* x0 = &xs[(0 * 4 + q) * 12];  // LDS broadcast reads
        const uint64_t* x1 = &xs[(1 * 4 + q) * 12];
#pragma unroll
        for (int j = 0; j < 4; ++j) {
            uint64_t t0 = x0[3 * j + 0] ^ Wv[3 * j + 0];
            uint64_t t1 = x0[3 * j + 1] ^ Wv[3 * j + 1];
            uint64_t t2 = x0[3 * j + 2] ^ Wv[3 * j + 2];
            acc0 += __popcll((t0 & t1) | (t2 & (t0 | t1)));
            uint64_t u0 = x1[3 * j + 0] ^ Wv[3 * j + 0];
            uint64_t u1 = x1[3 * j + 1] ^ Wv[3 * j + 1];
            uint64_t u2 = x1[3 * j + 2] ^ Wv[3 * j + 2];
            acc1 += __popcll((u0 & u1) | (u2 & (u0 | u1)));
        }
    }
    out[(size_t)(b0 + 0) * C_OUT + c] = 2304.0f - 4.5f * (float)acc0;
    out[(size_t)(b0 + 1) * C_OUT + c] = 2304.0f - 4.5f * (float)acc1;
}

extern "C" void kernel_launch(void* const* d_in, const int* in_sizes, int n_in,
                              void* d_out, int out_size, void* d_ws, size_t ws_size,
                              hipStream_t stream) {
    const float* x = (const float*)d_in[0];   // [256, 3072] f32
    const float* w = (const float*)d_in[1];   // [1024, 3072] f32
    float* out = (float*)d_out;               // [256, 1024] f32

    uint64_t* wpk = (uint64_t*)d_ws;          // 4*1024*12*8 = 393216 B

    pack_w<<<1024, 256, 0, stream>>>(w, wpk);
    maj_main<<<512, 256, 0, stream>>>(x, wpk, out);
}